// Round 2
// baseline (6733.668 us; speedup 1.0000x reference)
//
#include <hip/hip_runtime.h>
#include <cstdint>
#include <cstddef>

#define SS 12
#define NN 16384
#define EE 262144
#define TT 3072          // SS*NN/BB

// ---------- helpers ----------
__device__ __forceinline__ float fast_sig(float x) {
    float e = __builtin_amdgcn_exp2f(-1.442695041f * x);   // exp(-x)
    return __builtin_amdgcn_rcpf(1.f + e);
}
__device__ __forceinline__ float fast_tanh(float x) {
    float e = __builtin_amdgcn_exp2f(2.885390082f * x);    // exp(2x); inf-safe
    return 1.f - 2.f * __builtin_amdgcn_rcpf(e + 1.f);
}
__device__ __forceinline__ unsigned short f2bf(float f) {
    unsigned int x = __float_as_uint(f);
    unsigned int r = (x + 0x7FFFu + ((x >> 16) & 1u)) >> 16;
    return (unsigned short)r;
}
__device__ __forceinline__ float bf2f(unsigned short u) {
    return __uint_as_float(((unsigned int)u) << 16);
}

// ---------- zero counts ----------
__global__ void k_zero(int* __restrict__ p) {
    p[blockIdx.x * 256 + threadIdx.x] = 0;
}

// ---------- CSR build ----------
__global__ void k_count(const int* __restrict__ adj, int* __restrict__ counts) {
    int i = blockIdx.x * 256 + threadIdx.x;          // over SS*EE
    int t = i / EE, e = i - t * EE;
    int dst = adj[(size_t)t * 2 * EE + e];
    atomicAdd(&counts[t * NN + dst], 1);
}

__global__ void k_scan(const int* __restrict__ counts, int* __restrict__ offs,
                       int* __restrict__ cursor) {
    __shared__ int sums[1024];
    int t = blockIdx.x, tid = threadIdx.x;
    const int per = NN / 1024;                       // 16
    int base = t * NN + tid * per;
    int local[16];
    int s = 0;
#pragma unroll
    for (int i = 0; i < per; i++) { local[i] = counts[base + i]; s += local[i]; }
    sums[tid] = s;
    __syncthreads();
    for (int off = 1; off < 1024; off <<= 1) {
        int v = (tid >= off) ? sums[tid - off] : 0;
        __syncthreads();
        sums[tid] += v;
        __syncthreads();
    }
    int run = sums[tid] - s;                         // exclusive
#pragma unroll
    for (int i = 0; i < per; i++) { offs[base + i] = run; cursor[base + i] = run; run += local[i]; }
}

__global__ void k_scatter(const int* __restrict__ adj, const float* __restrict__ vals,
                          int* __restrict__ cursor, int2* __restrict__ edges) {
    int i = blockIdx.x * 256 + threadIdx.x;
    int t = i / EE, e = i - t * EE;
    int dst = adj[(size_t)t * 2 * EE + e];
    int src = adj[(size_t)t * 2 * EE + EE + e];
    float v = vals[(size_t)t * EE + e];
    int p = atomicAdd(&cursor[t * NN + dst], 1);
    edges[(size_t)t * EE + p] = make_int2(src, __float_as_int(v));
}

// ---------- support = xs @ gcn_weight  (fp32 acc, bf16 out) ----------
__global__ __launch_bounds__(256) void k_support(const float* __restrict__ xs,
                                                 const float* __restrict__ W,
                                                 unsigned short* __restrict__ sup) {
    __shared__ float Ash[64][128];
    __shared__ float Wsh[128][128];
    int tid = threadIdx.x;
    size_t rowbase = (size_t)blockIdx.x * 64;
    const float4* xa = (const float4*)(xs + rowbase * 128);
    float4* As = (float4*)&Ash[0][0];
#pragma unroll
    for (int q = 0; q < 8; q++) As[tid + q * 256] = xa[tid + q * 256];
    const float4* wg = (const float4*)W;
    float4* Ws = (float4*)&Wsh[0][0];
#pragma unroll
    for (int q = 0; q < 16; q++) Ws[tid + q * 256] = wg[tid + q * 256];
    __syncthreads();
    int jg = tid & 31, rg = tid >> 5;
    float acc[8][4];
#pragma unroll
    for (int i = 0; i < 8; i++)
#pragma unroll
        for (int j = 0; j < 4; j++) acc[i][j] = 0.f;
    for (int k4 = 0; k4 < 128; k4 += 4) {
        float4 a[8];
#pragma unroll
        for (int i = 0; i < 8; i++) a[i] = *(const float4*)&Ash[rg * 8 + i][k4];
#pragma unroll
        for (int kk = 0; kk < 4; kk++) {
            float4 wv = *(const float4*)&Wsh[k4 + kk][jg * 4];
#pragma unroll
            for (int i = 0; i < 8; i++) {
                float av = (kk == 0) ? a[i].x : (kk == 1) ? a[i].y : (kk == 2) ? a[i].z : a[i].w;
                acc[i][0] += av * wv.x; acc[i][1] += av * wv.y;
                acc[i][2] += av * wv.z; acc[i][3] += av * wv.w;
            }
        }
    }
#pragma unroll
    for (int i = 0; i < 8; i++) {
        ushort4 o;
        o.x = f2bf(acc[i][0]); o.y = f2bf(acc[i][1]);
        o.z = f2bf(acc[i][2]); o.w = f2bf(acc[i][3]);
        *(ushort4*)&sup[(rowbase + rg * 8 + i) * 128 + jg * 4] = o;
    }
}

// ---------- gather-reduce per node + bias + relu (bf16 in/out, fp32 acc) ----------
__global__ void k_gather(const int2* __restrict__ edges, const int* __restrict__ offs,
                         const int* __restrict__ ends,
                         const unsigned short* __restrict__ sup,
                         const float* __restrict__ bias,
                         unsigned short* __restrict__ cur) {
    int bn = blockIdx.x;                  // t*NN + n
    int t = bn >> 14;
    int j = threadIdx.x;
    int beg = offs[bn];
    int end = ends[bn];                   // cursor after scatter = beg + cnt
    const unsigned short* supt = sup + (size_t)t * NN * 128;
    const int2* eg = edges + (size_t)t * EE;
    float acc = 0.f;
    int p = beg;
    for (; p + 1 < end; p += 2) {
        int2 e0 = eg[p], e1 = eg[p + 1];
        acc += __int_as_float(e0.y) * bf2f(supt[(size_t)e0.x * 128 + j]);
        acc += __int_as_float(e1.y) * bf2f(supt[(size_t)e1.x * 128 + j]);
    }
    if (p < end) {
        int2 e0 = eg[p];
        acc += __int_as_float(e0.y) * bf2f(supt[(size_t)e0.x * 128 + j]);
    }
    float r = acc + bias[j];
    cur[(size_t)bn * 128 + j] = f2bf(r > 0.f ? r : 0.f);
}

// ---------- gates_x = cur @ w_ih^T + (b_ih + b_hh), stored bf16 ----------
__global__ __launch_bounds__(256) void k_xgates(const unsigned short* __restrict__ cur,
                                                const float* __restrict__ wih,
                                                const float* __restrict__ bih,
                                                const float* __restrict__ bhh,
                                                unsigned short* __restrict__ gx) {
    __shared__ float Ash[64][128];
    __shared__ float Bsh[128 * 129];      // [g_local][k], stride 129 breaks conflicts
    int tid = threadIdx.x;
    size_t rowbase = (size_t)blockIdx.x * 64;
    int gbase = blockIdx.y * 128;
    // A tile: 64x128 bf16 -> fp32 LDS
    const ushort4* xa = (const ushort4*)(cur + rowbase * 128);
    float* As = &Ash[0][0];
#pragma unroll
    for (int q = 0; q < 8; q++) {
        int f = tid + q * 256;            // ushort4 index, 0..2047
        ushort4 v = xa[f];
        float* dst = As + f * 4;
        dst[0] = bf2f(v.x); dst[1] = bf2f(v.y); dst[2] = bf2f(v.z); dst[3] = bf2f(v.w);
    }
    const float4* wg = (const float4*)(wih + (size_t)gbase * 128);
#pragma unroll
    for (int q = 0; q < 16; q++) {
        int f = tid + q * 256;            // float4 index, 0..4095
        float4 v = wg[f];
        int g = f >> 5;
        int kq = (f & 31) << 2;
        float* dst = &Bsh[g * 129 + kq];
        dst[0] = v.x; dst[1] = v.y; dst[2] = v.z; dst[3] = v.w;
    }
    __syncthreads();
    int jg = tid & 31, rg = tid >> 5;
    float acc[8][4];
#pragma unroll
    for (int i = 0; i < 8; i++)
#pragma unroll
        for (int j = 0; j < 4; j++) acc[i][j] = 0.f;
    for (int k4 = 0; k4 < 128; k4 += 4) {
        float4 a[8];
#pragma unroll
        for (int i = 0; i < 8; i++) a[i] = *(const float4*)&Ash[rg * 8 + i][k4];
#pragma unroll
        for (int c = 0; c < 4; c++) {
            const float* brow = &Bsh[(jg * 4 + c) * 129 + k4];
            float b0 = brow[0], b1 = brow[1], b2 = brow[2], b3 = brow[3];
#pragma unroll
            for (int i = 0; i < 8; i++) {
                acc[i][c] += a[i].x * b0 + a[i].y * b1 + a[i].z * b2 + a[i].w * b3;
            }
        }
    }
    float bs[4];
#pragma unroll
    for (int c = 0; c < 4; c++) bs[c] = bih[gbase + jg * 4 + c] + bhh[gbase + jg * 4 + c];
#pragma unroll
    for (int i = 0; i < 8; i++) {
        ushort4 o;
        o.x = f2bf(acc[i][0] + bs[0]);
        o.y = f2bf(acc[i][1] + bs[1]);
        o.z = f2bf(acc[i][2] + bs[2]);
        o.w = f2bf(acc[i][3] + bs[3]);
        *(ushort4*)&gx[(rowbase + rg * 8 + i) * 512 + gbase + jg * 4] = o;
    }
}

// ---------- persistent LSTM: 64 blocks (one per batch row), 256 threads ----------
__global__ __launch_bounds__(256, 1) void k_lstm(const unsigned short* __restrict__ gx,
                                                 const float* __restrict__ whh,
                                                 const float* __restrict__ h0,
                                                 const float* __restrict__ c0,
                                                 float* __restrict__ out) {
    __shared__ float hsh[128];
    __shared__ float gsh[512];
    int b = blockIdx.x, tid = threadIdx.x;

    // thread owns w_hh rows tid and tid+256, held in VGPRs
    float w0[128], w1[128];
    {
        const float4* r0 = (const float4*)(whh + (size_t)tid * 128);
        const float4* r1 = (const float4*)(whh + (size_t)(tid + 256) * 128);
#pragma unroll
        for (int q = 0; q < 32; q++) {
            float4 v = r0[q];
            w0[4 * q] = v.x; w0[4 * q + 1] = v.y; w0[4 * q + 2] = v.z; w0[4 * q + 3] = v.w;
        }
#pragma unroll
        for (int q = 0; q < 32; q++) {
            float4 v = r1[q];
            w1[4 * q] = v.x; w1[4 * q + 1] = v.y; w1[4 * q + 2] = v.z; w1[4 * q + 3] = v.w;
        }
    }
    float c = 0.f;
    if (tid < 128) {
        hsh[tid] = h0[(size_t)b * 128 + tid];
        c = c0[(size_t)b * 128 + tid];
    }
    __syncthreads();

    // prefetch gates_x row for step 0
    unsigned short n0, n1;
    {
        const unsigned short* gr = gx + (size_t)b * 512;
        n0 = gr[tid]; n1 = gr[tid + 256];
    }

    for (int t = 0; t < TT; t++) {
        float px0 = bf2f(n0), px1 = bf2f(n1);
        if (t + 1 < TT) {
            const unsigned short* gn = gx + ((size_t)(t + 1) * 64 + b) * 512;
            n0 = gn[tid]; n1 = gn[tid + 256];
        }
        // matvec: gates[tid] & gates[tid+256] from h
        float a0 = 0.f, a1 = 0.f;
#pragma unroll
        for (int k4 = 0; k4 < 128; k4 += 4) {
            float4 h4 = *(const float4*)&hsh[k4];
            a0 += w0[k4] * h4.x;     a1 += w1[k4] * h4.x;
            a0 += w0[k4 + 1] * h4.y; a1 += w1[k4 + 1] * h4.y;
            a0 += w0[k4 + 2] * h4.z; a1 += w1[k4 + 2] * h4.z;
            a0 += w0[k4 + 3] * h4.w; a1 += w1[k4 + 3] * h4.w;
        }
        gsh[tid] = a0 + px0;
        gsh[tid + 256] = a1 + px1;
        __syncthreads();
        if (tid < 128) {
            float ig = gsh[tid];
            float fg = gsh[128 + tid];
            float gg = gsh[256 + tid];
            float og = gsh[384 + tid];
            c = fast_sig(fg) * c + fast_sig(ig) * fast_tanh(gg);
            float hn = fast_sig(og) * fast_tanh(c);
            out[((size_t)t * 64 + b) * 128 + tid] = hn;
            hsh[tid] = hn;
        }
        __syncthreads();
    }
}

// ---------- launcher ----------
extern "C" void kernel_launch(void* const* d_in, const int* in_sizes, int n_in,
                              void* d_out, int out_size, void* d_ws, size_t ws_size,
                              hipStream_t stream) {
    const int* adj    = (const int*)d_in[0];
    const float* vals = (const float*)d_in[1];
    const float* xs   = (const float*)d_in[2];
    const float* gw   = (const float*)d_in[3];
    const float* gb   = (const float*)d_in[4];
    const float* wih  = (const float*)d_in[5];
    const float* whh  = (const float*)d_in[6];
    const float* bih  = (const float*)d_in[7];
    const float* bhh  = (const float*)d_in[8];
    const float* h0   = (const float*)d_in[9];
    const float* c0   = (const float*)d_in[10];
    float* out = (float*)d_out;

    // Workspace layout (peak concurrent = 251,658,240 B):
    //   [0,              50,331,648)  cur  (bf16, S*N*128)
    //   [50,331,648,    251,658,240)  gx   (bf16, S*N*512)
    // Aliased INSIDE the gx region (dead before k_xgates writes gx;
    // stream order guarantees no overlap in time):
    //   support @ gx+0          (50,331,648 B, bf16 S*N*128)
    //   counts  @ gx+50,331,648 (786,432 B)
    //   offs    @ gx+51,118,080 (786,432 B)
    //   cursor  @ gx+51,904,512 (786,432 B)
    //   edges   @ gx+52,690,944 (25,165,824 B, int2 S*E)
    char* ws = (char*)d_ws;
    unsigned short* cur = (unsigned short*)(ws);
    unsigned short* gx  = (unsigned short*)(ws + 50331648);
    unsigned short* sup = (unsigned short*)(ws + 50331648);
    int* counts         = (int*)(ws + 100663296);
    int* offs           = (int*)(ws + 101449728);
    int* cursor         = (int*)(ws + 102236160);
    int2* edges         = (int2*)(ws + 103022592);

    k_zero<<<(SS * NN) / 256, 256, 0, stream>>>(counts);
    k_count<<<(SS * EE) / 256, 256, 0, stream>>>(adj, counts);
    k_scan<<<SS, 1024, 0, stream>>>(counts, offs, cursor);
    k_scatter<<<(SS * EE) / 256, 256, 0, stream>>>(adj, vals, cursor, edges);
    k_support<<<(SS * NN) / 64, 256, 0, stream>>>(xs, gw, sup);
    k_gather<<<SS * NN, 128, 0, stream>>>(edges, offs, cursor, sup, gb, cur);
    k_xgates<<<dim3((SS * NN) / 64, 4), 256, 0, stream>>>(cur, wih, bih, bhh, gx);
    k_lstm<<<64, 256, 0, stream>>>(gx, whh, h0, c0, out);
}

// Round 3
// 2878.039 us; speedup vs baseline: 2.3397x; 2.3397x over previous
//
#include <hip/hip_runtime.h>
#include <cstdint>
#include <cstddef>

#define SS 12
#define NN 16384
#define EE 262144
#define TT 3072          // SS*NN/BB

typedef _Float16 h2_t __attribute__((ext_vector_type(2)));
typedef short bf16x8 __attribute__((ext_vector_type(8)));
typedef float floatx4 __attribute__((ext_vector_type(4)));
typedef unsigned short ushortx8 __attribute__((ext_vector_type(8)));

// ---------- helpers ----------
__device__ __forceinline__ float fast_sig(float x) {
    float e = __builtin_amdgcn_exp2f(-1.442695041f * x);   // exp(-x)
    return __builtin_amdgcn_rcpf(1.f + e);
}
__device__ __forceinline__ float fast_tanh(float x) {
    float e = __builtin_amdgcn_exp2f(2.885390082f * x);    // exp(2x); inf-safe
    return 1.f - 2.f * __builtin_amdgcn_rcpf(e + 1.f);
}
__device__ __forceinline__ unsigned short f2bf(float f) {
    unsigned int x = __float_as_uint(f);
    unsigned int r = (x + 0x7FFFu + ((x >> 16) & 1u)) >> 16;
    return (unsigned short)r;
}
__device__ __forceinline__ float bf2f(unsigned short u) {
    return __uint_as_float(((unsigned int)u) << 16);
}
__device__ __forceinline__ h2_t u2h(unsigned int u) {
    union { unsigned int u; h2_t h; } c; c.u = u; return c.h;
}

// ---------- zero counts ----------
__global__ void k_zero(int* __restrict__ p) {
    p[blockIdx.x * 256 + threadIdx.x] = 0;
}

// ---------- CSR build ----------
__global__ void k_count(const int* __restrict__ adj, int* __restrict__ counts) {
    int i = blockIdx.x * 256 + threadIdx.x;          // over SS*EE
    int t = i / EE, e = i - t * EE;
    int dst = adj[(size_t)t * 2 * EE + e];
    atomicAdd(&counts[t * NN + dst], 1);
}

__global__ void k_scan(const int* __restrict__ counts, int* __restrict__ offs,
                       int* __restrict__ cursor) {
    __shared__ int sums[1024];
    int t = blockIdx.x, tid = threadIdx.x;
    const int per = NN / 1024;                       // 16
    int base = t * NN + tid * per;
    int local[16];
    int s = 0;
#pragma unroll
    for (int i = 0; i < per; i++) { local[i] = counts[base + i]; s += local[i]; }
    sums[tid] = s;
    __syncthreads();
    for (int off = 1; off < 1024; off <<= 1) {
        int v = (tid >= off) ? sums[tid - off] : 0;
        __syncthreads();
        sums[tid] += v;
        __syncthreads();
    }
    int run = sums[tid] - s;                         // exclusive
#pragma unroll
    for (int i = 0; i < per; i++) { offs[base + i] = run; cursor[base + i] = run; run += local[i]; }
}

__global__ void k_scatter(const int* __restrict__ adj, const float* __restrict__ vals,
                          int* __restrict__ cursor, int2* __restrict__ edges) {
    int i = blockIdx.x * 256 + threadIdx.x;
    int t = i / EE, e = i - t * EE;
    int dst = adj[(size_t)t * 2 * EE + e];
    int src = adj[(size_t)t * 2 * EE + EE + e];
    float v = vals[(size_t)t * EE + e];
    int p = atomicAdd(&cursor[t * NN + dst], 1);
    edges[(size_t)t * EE + p] = make_int2(src, __float_as_int(v));
}

// ---------- support = xs @ gcn_weight  (fp32 acc, bf16 out) ----------
__global__ __launch_bounds__(256) void k_support(const float* __restrict__ xs,
                                                 const float* __restrict__ W,
                                                 unsigned short* __restrict__ sup) {
    __shared__ float Ash[64][128];
    __shared__ float Wsh[128][128];
    int tid = threadIdx.x;
    size_t rowbase = (size_t)blockIdx.x * 64;
    const float4* xa = (const float4*)(xs + rowbase * 128);
    float4* As = (float4*)&Ash[0][0];
#pragma unroll
    for (int q = 0; q < 8; q++) As[tid + q * 256] = xa[tid + q * 256];
    const float4* wg = (const float4*)W;
    float4* Ws = (float4*)&Wsh[0][0];
#pragma unroll
    for (int q = 0; q < 16; q++) Ws[tid + q * 256] = wg[tid + q * 256];
    __syncthreads();
    int jg = tid & 31, rg = tid >> 5;
    float acc[8][4];
#pragma unroll
    for (int i = 0; i < 8; i++)
#pragma unroll
        for (int j = 0; j < 4; j++) acc[i][j] = 0.f;
    for (int k4 = 0; k4 < 128; k4 += 4) {
        float4 a[8];
#pragma unroll
        for (int i = 0; i < 8; i++) a[i] = *(const float4*)&Ash[rg * 8 + i][k4];
#pragma unroll
        for (int kk = 0; kk < 4; kk++) {
            float4 wv = *(const float4*)&Wsh[k4 + kk][jg * 4];
#pragma unroll
            for (int i = 0; i < 8; i++) {
                float av = (kk == 0) ? a[i].x : (kk == 1) ? a[i].y : (kk == 2) ? a[i].z : a[i].w;
                acc[i][0] += av * wv.x; acc[i][1] += av * wv.y;
                acc[i][2] += av * wv.z; acc[i][3] += av * wv.w;
            }
        }
    }
#pragma unroll
    for (int i = 0; i < 8; i++) {
        ushort4 o;
        o.x = f2bf(acc[i][0]); o.y = f2bf(acc[i][1]);
        o.z = f2bf(acc[i][2]); o.w = f2bf(acc[i][3]);
        *(ushort4*)&sup[(rowbase + rg * 8 + i) * 128 + jg * 4] = o;
    }
}

// ---------- gather-reduce: 2 nodes per 256-thr block ----------
__global__ __launch_bounds__(256) void k_gather(const int2* __restrict__ edges,
                         const int* __restrict__ offs,
                         const int* __restrict__ ends,
                         const unsigned short* __restrict__ sup,
                         const float* __restrict__ bias,
                         unsigned short* __restrict__ cur) {
    int bn = blockIdx.x * 2 + (threadIdx.x >> 7);    // t*NN + n
    int t = bn >> 14;
    int j = threadIdx.x & 127;
    int beg = offs[bn];
    int end = ends[bn];                   // cursor after scatter = beg + cnt
    const unsigned short* supt = sup + (size_t)t * NN * 128;
    const int2* eg = edges + (size_t)t * EE;
    float acc = 0.f;
    int p = beg;
    for (; p + 1 < end; p += 2) {
        int2 e0 = eg[p], e1 = eg[p + 1];
        acc += __int_as_float(e0.y) * bf2f(supt[(size_t)e0.x * 128 + j]);
        acc += __int_as_float(e1.y) * bf2f(supt[(size_t)e1.x * 128 + j]);
    }
    if (p < end) {
        int2 e0 = eg[p];
        acc += __int_as_float(e0.y) * bf2f(supt[(size_t)e0.x * 128 + j]);
    }
    float r = acc + bias[j];
    cur[(size_t)bn * 128 + j] = f2bf(r > 0.f ? r : 0.f);
}

// ---------- gates_x = cur @ w_ih^T + (b_ih+b_hh), bf16 MFMA ----------
// grid (3072, 8), 256 thr. Block: rows 64 (M), gates 64 (N), K=128.
__global__ __launch_bounds__(256) void k_xgates(const unsigned short* __restrict__ cur,
                                                const float* __restrict__ wih,
                                                const float* __restrict__ bih,
                                                const float* __restrict__ bhh,
                                                unsigned short* __restrict__ gx) {
    __shared__ __align__(16) unsigned short At[64][136];   // +8 pad: 2-way banks
    __shared__ __align__(16) unsigned short Bt[64][136];
    int tid = threadIdx.x;
    size_t rowbase = (size_t)blockIdx.x * 64;
    int gbase = blockIdx.y * 64;
    // A tile: 64x128 bf16, 16B chunks
#pragma unroll
    for (int q = 0; q < 4; q++) {
        int idx = tid + q * 256;          // 0..1023 (16 chunks per row)
        int r = idx >> 4;
        int cc = (idx & 15) * 8;
        *(ushortx8*)&At[r][cc] = *(const ushortx8*)&cur[(rowbase + r) * 128 + cc];
    }
    // B tile: wih rows gbase..gbase+64, fp32 -> bf16 on the fly
#pragma unroll
    for (int q = 0; q < 8; q++) {
        int idx = tid + q * 256;          // 0..2047 (32 float4 per row)
        int r = idx >> 5;
        int c4 = (idx & 31) * 4;
        float4 v = *(const float4*)&wih[(size_t)(gbase + r) * 128 + c4];
        ushort4 o;
        o.x = f2bf(v.x); o.y = f2bf(v.y); o.z = f2bf(v.z); o.w = f2bf(v.w);
        *(ushort4*)&Bt[r][c4] = o;
    }
    __syncthreads();
    int wave = tid >> 6, lane = tid & 63;
    int m0 = wave * 16;
    int rin = lane & 15;
    int koff = (lane >> 4) * 8;
    floatx4 acc[4];
#pragma unroll
    for (int n = 0; n < 4; n++) acc[n] = (floatx4){0.f, 0.f, 0.f, 0.f};
#pragma unroll
    for (int kc = 0; kc < 4; kc++) {
        bf16x8 a = *(const bf16x8*)&At[m0 + rin][kc * 32 + koff];
#pragma unroll
        for (int n = 0; n < 4; n++) {
            bf16x8 b = *(const bf16x8*)&Bt[n * 16 + rin][kc * 32 + koff];
            acc[n] = __builtin_amdgcn_mfma_f32_16x16x32_bf16(a, b, acc[n], 0, 0, 0);
        }
    }
    // C/D: col = lane&15, row = (lane>>4)*4 + reg
    int rq = (lane >> 4) * 4;
#pragma unroll
    for (int n = 0; n < 4; n++) {
        int gcol = gbase + n * 16 + rin;
        float bs = bih[gcol] + bhh[gcol];
#pragma unroll
        for (int i = 0; i < 4; i++) {
            size_t row = rowbase + m0 + rq + i;
            gx[row * 512 + gcol] = f2bf(acc[n][i] + bs);
        }
    }
}

// ---------- persistent LSTM: 64 blocks x 512 thr, one gate row per thread ----
// w_hh row in 64 packed-f16 VGPRs; v_dot2_f32_f16 matvec; fp32 everywhere else.
__global__ __launch_bounds__(512, 2) void k_lstm(const unsigned short* __restrict__ gx,
                                                 const float* __restrict__ whh,
                                                 const float* __restrict__ h0,
                                                 const float* __restrict__ c0,
                                                 float* __restrict__ out) {
    __shared__ __align__(16) _Float16 hsh[128];   // h in packed f16
    __shared__ float gsh[512];
    int b = blockIdx.x, g = threadIdx.x;

    // pack w_hh row g into 64 f16-pairs (64 VGPRs)
    h2_t wpk[64];
    {
        const float4* r0 = (const float4*)(whh + (size_t)g * 128);
#pragma unroll
        for (int q = 0; q < 32; q++) {
            float4 v = r0[q];
            h2_t p0; p0.x = (_Float16)v.x; p0.y = (_Float16)v.y;
            h2_t p1; p1.x = (_Float16)v.z; p1.y = (_Float16)v.w;
            wpk[2 * q] = p0; wpk[2 * q + 1] = p1;
        }
    }
    float c = 0.f;
    if (g < 128) {
        hsh[g] = (_Float16)h0[(size_t)b * 128 + g];
        c = c0[(size_t)b * 128 + g];
    }
    __syncthreads();

    // prefetch gx two steps deep (covers ~900cyc HBM latency before vmcnt drain)
    unsigned short nA = gx[(size_t)b * 512 + g];
    unsigned short nB = gx[((size_t)64 + b) * 512 + g];

    float hh[8];
    for (int t8 = 0; t8 < TT; t8 += 8) {
#pragma unroll
        for (int q = 0; q < 8; q++) {
            int t = t8 + q;
            float px = bf2f(nA);
            int tp2 = (t + 2 < TT) ? t + 2 : TT - 1;
            unsigned short nC = gx[((size_t)tp2 * 64 + b) * 512 + g];
            // dot(w_hh[g], h) via f16 dot2, fp32 acc, 2 chains
            float a0 = 0.f, a1 = 0.f;
            const uint4* hp = (const uint4*)hsh;
#pragma unroll
            for (int mm = 0; mm < 16; mm++) {
                uint4 hv = hp[mm];
                a0 = __builtin_amdgcn_fdot2(wpk[4 * mm + 0], u2h(hv.x), a0, false);
                a1 = __builtin_amdgcn_fdot2(wpk[4 * mm + 1], u2h(hv.y), a1, false);
                a0 = __builtin_amdgcn_fdot2(wpk[4 * mm + 2], u2h(hv.z), a0, false);
                a1 = __builtin_amdgcn_fdot2(wpk[4 * mm + 3], u2h(hv.w), a1, false);
            }
            gsh[g] = a0 + a1 + px;
            __syncthreads();
            if (g < 128) {
                float ig = gsh[g];
                float fg = gsh[128 + g];
                float gg = gsh[256 + g];
                float og = gsh[384 + g];
                c = fast_sig(fg) * c + fast_sig(ig) * fast_tanh(gg);
                float hn = fast_sig(og) * fast_tanh(c);
                hh[q] = hn;
                hsh[g] = (_Float16)hn;
            }
            __syncthreads();
            nA = nB; nB = nC;
        }
        if (g < 128) {
#pragma unroll
            for (int q = 0; q < 8; q++)
                out[((size_t)(t8 + q) * 64 + b) * 128 + g] = hh[q];
        }
    }
}

// ---------- launcher ----------
extern "C" void kernel_launch(void* const* d_in, const int* in_sizes, int n_in,
                              void* d_out, int out_size, void* d_ws, size_t ws_size,
                              hipStream_t stream) {
    const int* adj    = (const int*)d_in[0];
    const float* vals = (const float*)d_in[1];
    const float* xs   = (const float*)d_in[2];
    const float* gw   = (const float*)d_in[3];
    const float* gb   = (const float*)d_in[4];
    const float* wih  = (const float*)d_in[5];
    const float* whh  = (const float*)d_in[6];
    const float* bih  = (const float*)d_in[7];
    const float* bhh  = (const float*)d_in[8];
    const float* h0   = (const float*)d_in[9];
    const float* c0   = (const float*)d_in[10];
    float* out = (float*)d_out;

    // Workspace layout (peak concurrent = 251,658,240 B):
    //   [0,              50,331,648)  cur  (bf16, S*N*128)
    //   [50,331,648,    251,658,240)  gx   (bf16, S*N*512)
    // Aliased INSIDE the gx region (dead before k_xgates writes gx):
    //   support @ gx+0, counts/offs/cursor/edges after it.
    char* ws = (char*)d_ws;
    unsigned short* cur = (unsigned short*)(ws);
    unsigned short* gx  = (unsigned short*)(ws + 50331648);
    unsigned short* sup = (unsigned short*)(ws + 50331648);
    int* counts         = (int*)(ws + 100663296);
    int* offs           = (int*)(ws + 101449728);
    int* cursor         = (int*)(ws + 102236160);
    int2* edges         = (int2*)(ws + 103022592);

    k_zero<<<(SS * NN) / 256, 256, 0, stream>>>(counts);
    k_count<<<(SS * EE) / 256, 256, 0, stream>>>(adj, counts);
    k_scan<<<SS, 1024, 0, stream>>>(counts, offs, cursor);
    k_scatter<<<(SS * EE) / 256, 256, 0, stream>>>(adj, vals, cursor, edges);
    k_support<<<(SS * NN) / 64, 256, 0, stream>>>(xs, gw, sup);
    k_gather<<<(SS * NN) / 2, 256, 0, stream>>>(edges, offs, cursor, sup, gb, cur);
    k_xgates<<<dim3((SS * NN) / 64, 8), 256, 0, stream>>>(cur, wih, bih, bhh, gx);
    k_lstm<<<64, 512, 0, stream>>>(gx, whh, h0, c0, out);
}

// Round 4
// 2800.133 us; speedup vs baseline: 2.4048x; 1.0278x over previous
//
#include <hip/hip_runtime.h>
#include <cstdint>
#include <cstddef>

#define SS 12
#define NN 16384
#define EE 262144
#define TT 3072          // SS*NN/BB

typedef _Float16 h2_t __attribute__((ext_vector_type(2)));
typedef short bf16x8 __attribute__((ext_vector_type(8)));
typedef float floatx4 __attribute__((ext_vector_type(4)));
typedef unsigned short ushortx8 __attribute__((ext_vector_type(8)));

// ---------- helpers ----------
__device__ __forceinline__ float fast_sig(float x) {
    float e = __builtin_amdgcn_exp2f(-1.442695041f * x);   // exp(-x)
    return __builtin_amdgcn_rcpf(1.f + e);
}
__device__ __forceinline__ float fast_tanh(float x) {
    float e = __builtin_amdgcn_exp2f(2.885390082f * x);    // exp(2x); inf-safe
    return 1.f - 2.f * __builtin_amdgcn_rcpf(e + 1.f);
}
__device__ __forceinline__ unsigned short f2bf(float f) {
    unsigned int x = __float_as_uint(f);
    unsigned int r = (x + 0x7FFFu + ((x >> 16) & 1u)) >> 16;
    return (unsigned short)r;
}
__device__ __forceinline__ float bf2f(unsigned short u) {
    return __uint_as_float(((unsigned int)u) << 16);
}
__device__ __forceinline__ h2_t u2h(unsigned int u) {
    union { unsigned int u; h2_t h; } c; c.u = u; return c.h;
}

// ---------- zero counts ----------
__global__ void k_zero(int* __restrict__ p) {
    p[blockIdx.x * 256 + threadIdx.x] = 0;
}

// ---------- CSR build ----------
__global__ void k_count(const int* __restrict__ adj, int* __restrict__ counts) {
    int i = blockIdx.x * 256 + threadIdx.x;          // over SS*EE
    int t = i / EE, e = i - t * EE;
    int dst = adj[(size_t)t * 2 * EE + e];
    atomicAdd(&counts[t * NN + dst], 1);
}

__global__ void k_scan(const int* __restrict__ counts, int* __restrict__ offs,
                       int* __restrict__ cursor) {
    __shared__ int sums[1024];
    int t = blockIdx.x, tid = threadIdx.x;
    const int per = NN / 1024;                       // 16
    int base = t * NN + tid * per;
    int local[16];
    int s = 0;
#pragma unroll
    for (int i = 0; i < per; i++) { local[i] = counts[base + i]; s += local[i]; }
    sums[tid] = s;
    __syncthreads();
    for (int off = 1; off < 1024; off <<= 1) {
        int v = (tid >= off) ? sums[tid - off] : 0;
        __syncthreads();
        sums[tid] += v;
        __syncthreads();
    }
    int run = sums[tid] - s;                         // exclusive
#pragma unroll
    for (int i = 0; i < per; i++) { offs[base + i] = run; cursor[base + i] = run; run += local[i]; }
}

__global__ void k_scatter(const int* __restrict__ adj, const float* __restrict__ vals,
                          int* __restrict__ cursor, int2* __restrict__ edges) {
    int i = blockIdx.x * 256 + threadIdx.x;
    int t = i / EE, e = i - t * EE;
    int dst = adj[(size_t)t * 2 * EE + e];
    int src = adj[(size_t)t * 2 * EE + EE + e];
    float v = vals[(size_t)t * EE + e];
    int p = atomicAdd(&cursor[t * NN + dst], 1);
    edges[(size_t)t * EE + p] = make_int2(src, __float_as_int(v));
}

// ---------- support = xs @ gcn_weight  (fp32 acc, bf16 out) ----------
__global__ __launch_bounds__(256) void k_support(const float* __restrict__ xs,
                                                 const float* __restrict__ W,
                                                 unsigned short* __restrict__ sup) {
    __shared__ float Ash[64][128];
    __shared__ float Wsh[128][128];
    int tid = threadIdx.x;
    size_t rowbase = (size_t)blockIdx.x * 64;
    const float4* xa = (const float4*)(xs + rowbase * 128);
    float4* As = (float4*)&Ash[0][0];
#pragma unroll
    for (int q = 0; q < 8; q++) As[tid + q * 256] = xa[tid + q * 256];
    const float4* wg = (const float4*)W;
    float4* Ws = (float4*)&Wsh[0][0];
#pragma unroll
    for (int q = 0; q < 16; q++) Ws[tid + q * 256] = wg[tid + q * 256];
    __syncthreads();
    int jg = tid & 31, rg = tid >> 5;
    float acc[8][4];
#pragma unroll
    for (int i = 0; i < 8; i++)
#pragma unroll
        for (int j = 0; j < 4; j++) acc[i][j] = 0.f;
    for (int k4 = 0; k4 < 128; k4 += 4) {
        float4 a[8];
#pragma unroll
        for (int i = 0; i < 8; i++) a[i] = *(const float4*)&Ash[rg * 8 + i][k4];
#pragma unroll
        for (int kk = 0; kk < 4; kk++) {
            float4 wv = *(const float4*)&Wsh[k4 + kk][jg * 4];
#pragma unroll
            for (int i = 0; i < 8; i++) {
                float av = (kk == 0) ? a[i].x : (kk == 1) ? a[i].y : (kk == 2) ? a[i].z : a[i].w;
                acc[i][0] += av * wv.x; acc[i][1] += av * wv.y;
                acc[i][2] += av * wv.z; acc[i][3] += av * wv.w;
            }
        }
    }
#pragma unroll
    for (int i = 0; i < 8; i++) {
        ushort4 o;
        o.x = f2bf(acc[i][0]); o.y = f2bf(acc[i][1]);
        o.z = f2bf(acc[i][2]); o.w = f2bf(acc[i][3]);
        *(ushort4*)&sup[(rowbase + rg * 8 + i) * 128 + jg * 4] = o;
    }
}

// ---------- gather-reduce: wave per node, 2 dims per lane ----------
__global__ __launch_bounds__(256) void k_gather(const int2* __restrict__ edges,
                         const int* __restrict__ offs,
                         const int* __restrict__ ends,
                         const unsigned short* __restrict__ sup,
                         const float* __restrict__ bias,
                         unsigned short* __restrict__ cur) {
    int bn = blockIdx.x * 4 + (threadIdx.x >> 6);     // t*NN + n, wave-uniform
    bn = __builtin_amdgcn_readfirstlane(bn);
    int t = bn >> 14;
    int l = threadIdx.x & 63;
    int beg = offs[bn];
    int end = ends[bn];
    const unsigned short* supt = sup + (size_t)t * NN * 128;
    const int2* eg = edges + (size_t)t * EE;
    float acc0 = 0.f, acc1 = 0.f;                     // dims 2l, 2l+1
    int p = beg;
    for (; p + 3 < end; p += 4) {
        int2 e0 = eg[p], e1 = eg[p + 1], e2 = eg[p + 2], e3 = eg[p + 3];
        unsigned int u0 = *(const unsigned int*)&supt[(size_t)e0.x * 128 + 2 * l];
        unsigned int u1 = *(const unsigned int*)&supt[(size_t)e1.x * 128 + 2 * l];
        unsigned int u2 = *(const unsigned int*)&supt[(size_t)e2.x * 128 + 2 * l];
        unsigned int u3 = *(const unsigned int*)&supt[(size_t)e3.x * 128 + 2 * l];
        float w0 = __int_as_float(e0.y), w1 = __int_as_float(e1.y);
        float w2 = __int_as_float(e2.y), w3 = __int_as_float(e3.y);
        acc0 += w0 * bf2f((unsigned short)u0); acc1 += w0 * bf2f((unsigned short)(u0 >> 16));
        acc0 += w1 * bf2f((unsigned short)u1); acc1 += w1 * bf2f((unsigned short)(u1 >> 16));
        acc0 += w2 * bf2f((unsigned short)u2); acc1 += w2 * bf2f((unsigned short)(u2 >> 16));
        acc0 += w3 * bf2f((unsigned short)u3); acc1 += w3 * bf2f((unsigned short)(u3 >> 16));
    }
    for (; p < end; p++) {
        int2 e0 = eg[p];
        unsigned int u0 = *(const unsigned int*)&supt[(size_t)e0.x * 128 + 2 * l];
        float w0 = __int_as_float(e0.y);
        acc0 += w0 * bf2f((unsigned short)u0);
        acc1 += w0 * bf2f((unsigned short)(u0 >> 16));
    }
    float r0 = acc0 + bias[2 * l];
    float r1 = acc1 + bias[2 * l + 1];
    ushort2 o;
    o.x = f2bf(r0 > 0.f ? r0 : 0.f);
    o.y = f2bf(r1 > 0.f ? r1 : 0.f);
    *(ushort2*)&cur[(size_t)bn * 128 + 2 * l] = o;
}

// ---------- gates_x = cur @ w_ih^T + (b_ih+b_hh), bf16 MFMA ----------
// grid (3072, 8), 256 thr. Block: rows 64 (M), gates 64 (N), K=128.
__global__ __launch_bounds__(256) void k_xgates(const unsigned short* __restrict__ cur,
                                                const float* __restrict__ wih,
                                                const float* __restrict__ bih,
                                                const float* __restrict__ bhh,
                                                unsigned short* __restrict__ gx) {
    __shared__ __align__(16) unsigned short At[64][136];   // +8 pad: 2-way banks
    __shared__ __align__(16) unsigned short Bt[64][136];
    int tid = threadIdx.x;
    size_t rowbase = (size_t)blockIdx.x * 64;
    int gbase = blockIdx.y * 64;
    // A tile: 64x128 bf16, 16B chunks
#pragma unroll
    for (int q = 0; q < 4; q++) {
        int idx = tid + q * 256;          // 0..1023 (16 chunks per row)
        int r = idx >> 4;
        int cc = (idx & 15) * 8;
        *(ushortx8*)&At[r][cc] = *(const ushortx8*)&cur[(rowbase + r) * 128 + cc];
    }
    // B tile: wih rows gbase..gbase+64, fp32 -> bf16 on the fly
#pragma unroll
    for (int q = 0; q < 8; q++) {
        int idx = tid + q * 256;          // 0..2047 (32 float4 per row)
        int r = idx >> 5;
        int c4 = (idx & 31) * 4;
        float4 v = *(const float4*)&wih[(size_t)(gbase + r) * 128 + c4];
        ushort4 o;
        o.x = f2bf(v.x); o.y = f2bf(v.y); o.z = f2bf(v.z); o.w = f2bf(v.w);
        *(ushort4*)&Bt[r][c4] = o;
    }
    __syncthreads();
    int wave = tid >> 6, lane = tid & 63;
    int m0 = wave * 16;
    int rin = lane & 15;
    int koff = (lane >> 4) * 8;
    floatx4 acc[4];
#pragma unroll
    for (int n = 0; n < 4; n++) acc[n] = (floatx4){0.f, 0.f, 0.f, 0.f};
#pragma unroll
    for (int kc = 0; kc < 4; kc++) {
        bf16x8 a = *(const bf16x8*)&At[m0 + rin][kc * 32 + koff];
#pragma unroll
        for (int n = 0; n < 4; n++) {
            bf16x8 b = *(const bf16x8*)&Bt[n * 16 + rin][kc * 32 + koff];
            acc[n] = __builtin_amdgcn_mfma_f32_16x16x32_bf16(a, b, acc[n], 0, 0, 0);
        }
    }
    // C/D: col = lane&15, row = (lane>>4)*4 + reg
    int rq = (lane >> 4) * 4;
#pragma unroll
    for (int n = 0; n < 4; n++) {
        int gcol = gbase + n * 16 + rin;
        float bs = bih[gcol] + bhh[gcol];
#pragma unroll
        for (int i = 0; i < 4; i++) {
            size_t row = rowbase + m0 + rq + i;
            gx[row * 512 + gcol] = f2bf(acc[n][i] + bs);
        }
    }
}

// ---------- persistent LSTM: 64 blocks x 256 thr, 2 gate rows per thread ----
// h broadcast via v_readlane -> SGPR -> v_dot2_f32_f16 (no LDS broadcast).
// Activations computed in the matvec lane (gate-local); only tanh(c) in the
// 128-lane final stage. 2 barriers/step.
__global__ __launch_bounds__(256, 1) void k_lstm(const unsigned short* __restrict__ gx,
                                                 const float* __restrict__ whh,
                                                 const float* __restrict__ h0,
                                                 const float* __restrict__ c0,
                                                 float* __restrict__ out) {
    __shared__ __align__(8) _Float16 hsh[128];   // h packed f16 pairs
    __shared__ float gsh[512];                   // activated gates
    int b = blockIdx.x, tid = threadIdx.x;
    int g1 = tid + 256;

    // weights: rows tid and tid+256, packed f16 pairs (64+64 = 128 VGPRs)
    h2_t w0[64], w1[64];
    {
        const float4* r0 = (const float4*)(whh + (size_t)tid * 128);
        const float4* r1 = (const float4*)(whh + (size_t)g1 * 128);
#pragma unroll
        for (int q = 0; q < 32; q++) {
            float4 v = r0[q];
            h2_t p0; p0.x = (_Float16)v.x; p0.y = (_Float16)v.y;
            h2_t p1; p1.x = (_Float16)v.z; p1.y = (_Float16)v.w;
            w0[2 * q] = p0; w0[2 * q + 1] = p1;
        }
#pragma unroll
        for (int q = 0; q < 32; q++) {
            float4 v = r1[q];
            h2_t p0; p0.x = (_Float16)v.x; p0.y = (_Float16)v.y;
            h2_t p1; p1.x = (_Float16)v.z; p1.y = (_Float16)v.w;
            w1[2 * q] = p0; w1[2 * q + 1] = p1;
        }
    }
    float c = 0.f;
    if (tid < 128) {
        hsh[tid] = (_Float16)h0[(size_t)b * 128 + tid];
        c = c0[(size_t)b * 128 + tid];
    }
    __syncthreads();

    // prefetch gx two steps deep
    unsigned short nA0 = gx[(size_t)b * 512 + tid];
    unsigned short nA1 = gx[(size_t)b * 512 + g1];
    unsigned short nB0 = gx[((size_t)64 + b) * 512 + tid];
    unsigned short nB1 = gx[((size_t)64 + b) * 512 + g1];

    int lane = tid & 63;
    float hh[8];
    for (int t8 = 0; t8 < TT; t8 += 8) {
#pragma unroll
        for (int q = 0; q < 8; q++) {
            int t = t8 + q;
            float px0 = bf2f(nA0), px1 = bf2f(nA1);
            int tp2 = (t + 2 < TT) ? t + 2 : TT - 1;
            const unsigned short* gp = gx + ((size_t)tp2 * 64 + b) * 512;
            unsigned short nC0 = gp[tid];
            unsigned short nC1 = gp[g1];
            // full h (128 f16) lives in this wave's 64 lanes as pairs
            unsigned int hv = *(const unsigned int*)&hsh[lane * 2];
            float a00 = 0.f, a01 = 0.f, a10 = 0.f, a11 = 0.f;
#pragma unroll
            for (int mm = 0; mm < 64; mm += 2) {
                unsigned int s0 = __builtin_amdgcn_readlane(hv, mm);
                unsigned int s1 = __builtin_amdgcn_readlane(hv, mm + 1);
                a00 = __builtin_amdgcn_fdot2(w0[mm], u2h(s0), a00, false);
                a10 = __builtin_amdgcn_fdot2(w1[mm], u2h(s0), a10, false);
                a01 = __builtin_amdgcn_fdot2(w0[mm + 1], u2h(s1), a01, false);
                a11 = __builtin_amdgcn_fdot2(w1[mm + 1], u2h(s1), a11, false);
            }
            float r0 = a00 + a01 + px0;              // gate tid   (i or f) -> sigmoid
            float r1 = a10 + a11 + px1;              // gate tid+256 (g or o)
            float act0 = fast_sig(r0);
            float act1 = (tid < 128) ? fast_tanh(r1) : fast_sig(r1);  // wave-uniform branch
            gsh[tid] = act0;
            gsh[g1] = act1;
            __syncthreads();
            if (tid < 128) {
                float ai = gsh[tid];
                float af = gsh[tid + 128];
                float ag = gsh[tid + 256];
                float ao = gsh[tid + 384];
                c = af * c + ai * ag;
                float hn = ao * fast_tanh(c);
                hh[q] = hn;
                hsh[tid] = (_Float16)hn;
            }
            __syncthreads();
            nA0 = nB0; nA1 = nB1; nB0 = nC0; nB1 = nC1;
        }
        if (tid < 128) {
#pragma unroll
            for (int q = 0; q < 8; q++)
                out[((size_t)(t8 + q) * 64 + b) * 128 + tid] = hh[q];
        }
    }
}

// ---------- launcher ----------
extern "C" void kernel_launch(void* const* d_in, const int* in_sizes, int n_in,
                              void* d_out, int out_size, void* d_ws, size_t ws_size,
                              hipStream_t stream) {
    const int* adj    = (const int*)d_in[0];
    const float* vals = (const float*)d_in[1];
    const float* xs   = (const float*)d_in[2];
    const float* gw   = (const float*)d_in[3];
    const float* gb   = (const float*)d_in[4];
    const float* wih  = (const float*)d_in[5];
    const float* whh  = (const float*)d_in[6];
    const float* bih  = (const float*)d_in[7];
    const float* bhh  = (const float*)d_in[8];
    const float* h0   = (const float*)d_in[9];
    const float* c0   = (const float*)d_in[10];
    float* out = (float*)d_out;

    // Workspace layout (peak concurrent = 251,658,240 B):
    //   [0, 50,331,648)             cur (bf16, S*N*128)
    //   [50,331,648, 251,658,240)   gx  (bf16, S*N*512)
    // Aliased INSIDE the gx region (dead before k_xgates writes gx):
    //   support @ gx+0, counts/offs/cursor/edges after it.
    char* ws = (char*)d_ws;
    unsigned short* cur = (unsigned short*)(ws);
    unsigned short* gx  = (unsigned short*)(ws + 50331648);
    unsigned short* sup = (unsigned short*)(ws + 50331648);
    int* counts         = (int*)(ws + 100663296);
    int* offs           = (int*)(ws + 101449728);
    int* cursor         = (int*)(ws + 102236160);
    int2* edges         = (int2*)(ws + 103022592);

    k_zero<<<(SS * NN) / 256, 256, 0, stream>>>(counts);
    k_count<<<(SS * EE) / 256, 256, 0, stream>>>(adj, counts);
    k_scan<<<SS, 1024, 0, stream>>>(counts, offs, cursor);
    k_scatter<<<(SS * EE) / 256, 256, 0, stream>>>(adj, vals, cursor, edges);
    k_support<<<(SS * NN) / 64, 256, 0, stream>>>(xs, gw, sup);
    k_gather<<<(SS * NN) / 4, 256, 0, stream>>>(edges, offs, cursor, sup, gb, cur);
    k_xgates<<<dim3((SS * NN) / 64, 8), 256, 0, stream>>>(cur, wih, bih, bhh, gx);
    k_lstm<<<64, 256, 0, stream>>>(gx, whh, h0, c0, out);
}